// Round 5
// baseline (510.055 us; speedup 1.0000x reference)
//
#include <hip/hip_runtime.h>
#include <hip/hip_bf16.h>
#include <cstddef>

// Problem constants
#define BB 256
#define XX 512
#define HH 1024
#define RR 512
#define MM 512
// derived
#define KCAT 2048          // X + H + R
#define KXC 1536           // X + H
#define NFULL 4608         // R + 4H
#define NG 1536            // R + H

// d_out offsets (floats)
#define OFF_NH (BB*1536)                 // 393216
#define OFF_NC (OFF_NH + BB*HH)          // 655360
#define OFF_HM (OFF_NC + BB*HH)          // 917504

typedef __attribute__((ext_vector_type(8))) short bf16x8;
typedef __attribute__((ext_vector_type(4))) short s16x4;
typedef __attribute__((ext_vector_type(4))) float f32x4;

__device__ __forceinline__ float sigm(float x) { return 1.0f / (1.0f + expf(-x)); }

// fp32 -> bf16 bits, round-to-nearest-even (finite values)
__device__ __forceinline__ unsigned short f2bf(float f) {
    unsigned u = __float_as_uint(f);
    u = u + 0x7fffu + ((u >> 16) & 1u);
    return (unsigned short)(u >> 16);
}
__device__ __forceinline__ float bf2f(unsigned short h) {
    return __uint_as_float((unsigned)h << 16);
}

// ===========================================================================
// ===============            MAIN (pre-split) PATH            ===============
// ===========================================================================

// Straight convert, two weights per launch: y=0 -> fc_w, y=1 -> trans_w.
// Both are [512][1536] f32 -> hi/lo bf16 same layout. 8 elems/thread.
__global__ __launch_bounds__(256) void convw_k(const float* __restrict__ s0,
                                               short* __restrict__ h0, short* __restrict__ l0,
                                               const float* __restrict__ s1,
                                               short* __restrict__ h1, short* __restrict__ l1) {
    const float* src = blockIdx.y ? s1 : s0;
    short* hi = blockIdx.y ? h1 : h0;
    short* lo = blockIdx.y ? l1 : l0;
    size_t e0 = ((size_t)blockIdx.x * 256 + threadIdx.x) * 8;
    short hs[8], ls[8];
    #pragma unroll
    for (int q = 0; q < 2; ++q) {
        float4 v = reinterpret_cast<const float4*>(src + e0)[q];
        float f[4] = {v.x, v.y, v.z, v.w};
        #pragma unroll
        for (int e = 0; e < 4; ++e) {
            unsigned short hb = f2bf(f[e]);
            hs[q * 4 + e] = (short)hb;
            ls[q * 4 + e] = (short)f2bf(f[e] - bf2f(hb));
        }
    }
    *reinterpret_cast<bf16x8*>(hi + e0) = *reinterpret_cast<bf16x8*>(&hs[0]);
    *reinterpret_cast<bf16x8*>(lo + e0) = *reinterpret_cast<bf16x8*>(&ls[0]);
}

// Transpose-convert both NN weights in one launch.
// grid (KCAT/64=32, 72+24=96): by<72 -> W_full [2048][4608], else W_full1 [2048][1536].
__global__ __launch_bounds__(256) void convt_k(const float* __restrict__ W0,
                                               short* __restrict__ T0hi, short* __restrict__ T0lo,
                                               const float* __restrict__ W1,
                                               short* __restrict__ T1hi, short* __restrict__ T1lo) {
    __shared__ __align__(16) short lh[64][72];
    __shared__ __align__(16) short ll[64][72];
    const int tid = threadIdx.x;
    const int by = blockIdx.y;
    const float* W;
    short *Thi, *Tlo;
    int Ndim, n0;
    if (by < 72) { W = W0; Thi = T0hi; Tlo = T0lo; Ndim = NFULL; n0 = by * 64; }
    else         { W = W1; Thi = T1hi; Tlo = T1lo; Ndim = NG;    n0 = (by - 72) * 64; }
    const int k0 = blockIdx.x * 64;
    {
        int kr = (tid >> 4) * 4;
        int nc = (tid & 15) * 4;
        #pragma unroll
        for (int i = 0; i < 4; ++i) {
            float4 v = *reinterpret_cast<const float4*>(W + (size_t)(k0 + kr + i) * Ndim + n0 + nc);
            float f[4] = {v.x, v.y, v.z, v.w};
            #pragma unroll
            for (int e = 0; e < 4; ++e) {
                unsigned short hb = f2bf(f[e]);
                lh[nc + e][kr + i] = (short)hb;
                ll[nc + e][kr + i] = (short)f2bf(f[e] - bf2f(hb));
            }
        }
    }
    __syncthreads();
    {
        int nl = tid >> 2;
        int kq = (tid & 3) * 16;
        size_t base = (size_t)(n0 + nl) * KCAT + k0 + kq;
        *reinterpret_cast<bf16x8*>(Thi + base)     = *reinterpret_cast<const bf16x8*>(&lh[nl][kq]);
        *reinterpret_cast<bf16x8*>(Thi + base + 8) = *reinterpret_cast<const bf16x8*>(&lh[nl][kq + 8]);
        *reinterpret_cast<bf16x8*>(Tlo + base)     = *reinterpret_cast<const bf16x8*>(&ll[nl][kq]);
        *reinterpret_cast<bf16x8*>(Tlo + base + 8) = *reinterpret_cast<const bf16x8*>(&ll[nl][kq + 8]);
    }
}

// prep: cat[:,0:1536] = [x|c] (hi/lo); x also into gat[:,0:512], xnc[:,0:512]
__global__ __launch_bounds__(256) void prep_k(const float* __restrict__ x,
                                              const float* __restrict__ c,
                                              short* __restrict__ cat_hi, short* __restrict__ cat_lo,
                                              short* __restrict__ gat_hi, short* __restrict__ gat_lo,
                                              short* __restrict__ xnc_hi, short* __restrict__ xnc_lo) {
    int i = blockIdx.x * 256 + threadIdx.x;       // B*1536/4 threads
    int e0 = i * 4;
    int b = e0 / KXC, q = e0 - b * KXC;
    float4 v = (q < XX) ? *reinterpret_cast<const float4*>(x + (size_t)b * XX + q)
                        : *reinterpret_cast<const float4*>(c + (size_t)b * HH + (q - XX));
    float f[4] = {v.x, v.y, v.z, v.w};
    s16x4 hv, lv;
    #pragma unroll
    for (int e = 0; e < 4; ++e) {
        unsigned short hb = f2bf(f[e]);
        hv[e] = (short)hb;
        lv[e] = (short)f2bf(f[e] - bf2f(hb));
    }
    *reinterpret_cast<s16x4*>(cat_hi + (size_t)b * KCAT + q) = hv;
    *reinterpret_cast<s16x4*>(cat_lo + (size_t)b * KCAT + q) = lv;
    if (q < XX) {
        *reinterpret_cast<s16x4*>(gat_hi + (size_t)b * KCAT + q) = hv;
        *reinterpret_cast<s16x4*>(gat_lo + (size_t)b * KCAT + q) = lv;
        *reinterpret_cast<s16x4*>(xnc_hi + (size_t)b * KXC + q) = hv;
        *reinterpret_cast<s16x4*>(xnc_lo + (size_t)b * KXC + q) = lv;
    }
}

// ---------------------------------------------------------------------------
// mgemm128: 128x128 tile, 4 waves (2x2), wave-tile 64x64 (4x4 frags of
// 16x16x32), BK=64, reg-prefetch double buffering, bf16 hi/lo 3-pass.
// A [row][lda] hi/lo; B [n][ldb] hi/lo (NT). Split-K via blockIdx.z:
// chunk z covers k in [z*kchunk, (z+1)*kchunk); writes raw partial to
// Cbase + z*chunk_stride; bias added only by chunk 0.
__global__ __launch_bounds__(256, 2) void mgemm128(const short* __restrict__ Ahi,
                                                   const short* __restrict__ Alo, int lda,
                                                   const short* __restrict__ Bhi,
                                                   const short* __restrict__ Blo, int ldb,
                                                   const float* __restrict__ bias,
                                                   float* __restrict__ Cbase, int ldc,
                                                   size_t chunk_stride, int kchunk) {
    __shared__ __align__(16) short Ah[128][72];
    __shared__ __align__(16) short Al[128][72];
    __shared__ __align__(16) short Bh[128][72];
    __shared__ __align__(16) short Bl[128][72];

    const int tid = threadIdx.x;
    const int col0 = blockIdx.x * 128, row0 = blockIdx.y * 128;
    const int z = blockIdx.z;
    const int kbeg = z * kchunk;
    float* C = Cbase + (size_t)z * chunk_stride;

    const int lane = tid & 63, w = tid >> 6;
    const int rm = (w >> 1) * 64, cn = (w & 1) * 64;
    const int fr = lane & 15, kg = lane >> 4;

    const int sr = tid >> 1;           // staging row 0..127
    const int sk = (tid & 1) * 32;     // k offset 0/32

    f32x4 acc[4][4] = {};
    int4 pa[8], pb[8];                 // prefetch regs: [0..3]=hi, [4..7]=lo

    const short* aH = Ahi + (size_t)(row0 + sr) * lda + sk;
    const short* aL = Alo + (size_t)(row0 + sr) * lda + sk;
    const short* bH = Bhi + (size_t)(col0 + sr) * ldb + sk;
    const short* bL = Blo + (size_t)(col0 + sr) * ldb + sk;

    const int steps = kchunk >> 6;

    // prologue load
    #pragma unroll
    for (int j = 0; j < 4; ++j) {
        pa[j]     = *reinterpret_cast<const int4*>(aH + kbeg + j * 8);
        pa[4 + j] = *reinterpret_cast<const int4*>(aL + kbeg + j * 8);
        pb[j]     = *reinterpret_cast<const int4*>(bH + kbeg + j * 8);
        pb[4 + j] = *reinterpret_cast<const int4*>(bL + kbeg + j * 8);
    }

    for (int t = 0; t < steps; ++t) {
        // write staged regs to LDS
        #pragma unroll
        for (int j = 0; j < 4; ++j) {
            *reinterpret_cast<int4*>(&Ah[sr][sk + j * 8]) = pa[j];
            *reinterpret_cast<int4*>(&Al[sr][sk + j * 8]) = pa[4 + j];
            *reinterpret_cast<int4*>(&Bh[sr][sk + j * 8]) = pb[j];
            *reinterpret_cast<int4*>(&Bl[sr][sk + j * 8]) = pb[4 + j];
        }
        __syncthreads();
        // issue next tile's loads (latency hidden under MFMA phase)
        if (t + 1 < steps) {
            int kc = kbeg + (t + 1) * 64;
            #pragma unroll
            for (int j = 0; j < 4; ++j) {
                pa[j]     = *reinterpret_cast<const int4*>(aH + kc + j * 8);
                pa[4 + j] = *reinterpret_cast<const int4*>(aL + kc + j * 8);
                pb[j]     = *reinterpret_cast<const int4*>(bH + kc + j * 8);
                pb[4 + j] = *reinterpret_cast<const int4*>(bL + kc + j * 8);
            }
        }
        // MFMA phase
        #pragma unroll
        for (int ks = 0; ks < 64; ks += 32) {
            bf16x8 ah[4], al[4], bh[4], bl[4];
            #pragma unroll
            for (int q = 0; q < 4; ++q) {
                ah[q] = *reinterpret_cast<const bf16x8*>(&Ah[rm + q * 16 + fr][ks + kg * 8]);
                al[q] = *reinterpret_cast<const bf16x8*>(&Al[rm + q * 16 + fr][ks + kg * 8]);
                bh[q] = *reinterpret_cast<const bf16x8*>(&Bh[cn + q * 16 + fr][ks + kg * 8]);
                bl[q] = *reinterpret_cast<const bf16x8*>(&Bl[cn + q * 16 + fr][ks + kg * 8]);
            }
            #pragma unroll
            for (int mf = 0; mf < 4; ++mf)
                #pragma unroll
                for (int nf = 0; nf < 4; ++nf) {
                    acc[mf][nf] = __builtin_amdgcn_mfma_f32_16x16x32_bf16(ah[mf], bh[nf], acc[mf][nf], 0, 0, 0);
                    acc[mf][nf] = __builtin_amdgcn_mfma_f32_16x16x32_bf16(ah[mf], bl[nf], acc[mf][nf], 0, 0, 0);
                    acc[mf][nf] = __builtin_amdgcn_mfma_f32_16x16x32_bf16(al[mf], bh[nf], acc[mf][nf], 0, 0, 0);
                }
        }
        __syncthreads();
    }

    // epilogue: C/D layout col=lane&15, row=(lane>>4)*4+i
    #pragma unroll
    for (int mf = 0; mf < 4; ++mf)
        #pragma unroll
        for (int nf = 0; nf < 4; ++nf)
            #pragma unroll
            for (int i = 0; i < 4; ++i) {
                int row = row0 + rm + mf * 16 + kg * 4 + i;
                int col = col0 + cn + nf * 16 + fr;
                float v = acc[mf][nf][i];
                if (z == 0) v += bias[col];
                C[(size_t)row * ldc + col] = v;
            }
}

// fused softmax + h_entry: sums 6 fc partials; block b, 512 threads.
__global__ __launch_bounds__(512) void smhe_k(const float* __restrict__ rhp,
                                              const float* __restrict__ hmem,
                                              float* __restrict__ hidx,
                                              short* __restrict__ cat_hi,
                                              short* __restrict__ cat_lo) {
    __shared__ float red[8];
    __shared__ float red2[8];
    __shared__ float wiL[MM];
    int b = blockIdx.x, t = threadIdx.x;
    float v = 0.f;
    #pragma unroll
    for (int zz = 0; zz < 6; ++zz) v += rhp[(size_t)zz * (BB * MM) + (size_t)b * MM + t];
    float m = v;
    #pragma unroll
    for (int off = 1; off < 64; off <<= 1) m = fmaxf(m, __shfl_xor(m, off));
    int wid = t >> 6, lane = t & 63;
    if (lane == 0) red[wid] = m;
    __syncthreads();
    float mm = red[0];
    #pragma unroll
    for (int i = 1; i < 8; ++i) mm = fmaxf(mm, red[i]);
    float e = expf(v - mm);
    float s = e;
    #pragma unroll
    for (int off = 1; off < 64; off <<= 1) s += __shfl_xor(s, off);
    if (lane == 0) red2[wid] = s;
    __syncthreads();
    float tot = red2[0];
    #pragma unroll
    for (int i = 1; i < 8; ++i) tot += red2[i];
    float wi = e / tot;
    hidx[(size_t)b * MM + t] = wi;
    wiL[t] = wi;
    __syncthreads();
    const float* hm = hmem + (size_t)b * MM * RR + t;
    float acc = 0.f;
    #pragma unroll 8
    for (int m2 = 0; m2 < MM; ++m2) acc += wiL[m2] * hm[(size_t)m2 * RR];
    size_t base = (size_t)b * KCAT + KXC + t;
    unsigned short hb = f2bf(acc);
    cat_hi[base] = (short)hb;
    cat_lo[base] = (short)f2bf(acc - bf2f(hb));
}

// gate finish: g = sigm(sum of 4 partials); gat[:,512:2048] = split(cat*g)
__global__ __launch_bounds__(256) void gfin_k(const float* __restrict__ gp,
                                              const short* __restrict__ cat_hi,
                                              const short* __restrict__ cat_lo,
                                              short* __restrict__ gat_hi,
                                              short* __restrict__ gat_lo) {
    int i = blockIdx.x * 256 + threadIdx.x;     // B*1536
    int b = i / NG, q = i - b * NG;
    float s = 0.f;
    #pragma unroll
    for (int zz = 0; zz < 4; ++zz) s += gp[(size_t)zz * (BB * NG) + (size_t)b * NG + q];
    size_t base = (size_t)b * KCAT + XX + q;
    float e = bf2f((unsigned short)cat_hi[base]) + bf2f((unsigned short)cat_lo[base]);
    float gv = e * sigm(s);
    unsigned short hb = f2bf(gv);
    gat_hi[base] = (short)hb;
    gat_lo[base] = (short)f2bf(gv - bf2f(hb));
}

// LSTM elementwise; sums 2 big-GEMM partials; writes outputs + xnc new_c part
__global__ __launch_bounds__(256) void lstm_k(const float* __restrict__ pre0,
                                              const float* __restrict__ c,
                                              const short* __restrict__ cat_hi,
                                              const short* __restrict__ cat_lo,
                                              float* __restrict__ out,
                                              short* __restrict__ xnc_hi,
                                              short* __restrict__ xnc_lo) {
    const float* pre1 = pre0 + (size_t)BB * NFULL;
    int idx = blockIdx.x * 256 + threadIdx.x;   // B*1536
    int b = idx / 1536, q = idx - b * 1536;
    size_t pb = (size_t)b * NFULL;
    if (q < HH) {
        float iv = pre0[pb + q] + pre1[pb + q];
        float jv = pre0[pb + HH + q] + pre1[pb + HH + q];
        float fv = pre0[pb + 2 * HH + q] + pre1[pb + 2 * HH + q];
        float ov = pre0[pb + 3 * HH + q] + pre1[pb + 3 * HH + q];
        float cc = c[(size_t)b * HH + q];
        float nc = tanhf(cc * sigm(fv + 1.0f) + sigm(iv) * tanhf(jv));
        float nh = nc * sigm(ov);
        out[(size_t)b * 1536 + q] = nh;
        out[OFF_NH + (size_t)b * HH + q] = nh;
        out[OFF_NC + (size_t)b * HH + q] = nc;
        unsigned short hb = f2bf(nc);
        xnc_hi[(size_t)b * KXC + XX + q] = (short)hb;
        xnc_lo[(size_t)b * KXC + XX + q] = (short)f2bf(nc - bf2f(hb));
    } else {
        int r = q - HH;
        float om = pre0[pb + 4 * HH + r] + pre1[pb + 4 * HH + r];
        size_t base = (size_t)b * KCAT + KXC + r;
        float he = bf2f((unsigned short)cat_hi[base]) + bf2f((unsigned short)cat_lo[base]);
        out[(size_t)b * 1536 + HH + r] = he * sigm(om);
    }
}

// new_hmem blend; sums 6 trans partials per (b,r) vector
__global__ __launch_bounds__(256) void hmemupd_k(const float* __restrict__ hmem,
                                                 const float* __restrict__ wvalp,
                                                 const float* __restrict__ widx,
                                                 float* __restrict__ outhm) {
    size_t n4 = (size_t)BB * MM * RR / 4;
    size_t stride = (size_t)gridDim.x * blockDim.x;
    for (size_t i = (size_t)blockIdx.x * blockDim.x + threadIdx.x; i < n4; i += stride) {
        size_t e = i * 4;
        int r = (int)(e & (RR - 1));
        int m = (int)((e >> 9) & (MM - 1));
        int b = (int)(e >> 18);
        float wi = widx[(size_t)b * MM + m];
        float om = 1.0f - wi;
        float4 hv = *reinterpret_cast<const float4*>(hmem + e);
        float4 wv = {0.f, 0.f, 0.f, 0.f};
        #pragma unroll
        for (int zz = 0; zz < 6; ++zz) {
            float4 p = *reinterpret_cast<const float4*>(wvalp + (size_t)zz * (BB * RR) + (size_t)b * RR + r);
            wv.x += p.x; wv.y += p.y; wv.z += p.z; wv.w += p.w;
        }
        float4 o;
        o.x = wv.x * wi + hv.x * om;
        o.y = wv.y * wi + hv.y * om;
        o.z = wv.z * wi + hv.z * om;
        o.w = wv.w * wi + hv.w * om;
        *reinterpret_cast<float4*>(outhm + e) = o;
    }
}

// ===========================================================================
// ===============     FALLBACK (round-3, split-in-loop)       ===============
// ===========================================================================

__global__ __launch_bounds__(256) void prep3_k(const float* __restrict__ x,
                                               const float* __restrict__ c,
                                               float* __restrict__ concatb,
                                               float* __restrict__ gated) {
    int idx = blockIdx.x * 256 + threadIdx.x;
    int b = idx / KXC, q = idx - b * KXC;
    float v;
    if (q < XX) { v = x[b * XX + q]; gated[(size_t)b * KCAT + q] = v; }
    else v = c[b * HH + (q - XX)];
    concatb[(size_t)b * KCAT + q] = v;
}

template<int AMODE, int BLAYOUT, int EPI>
__global__ __launch_bounds__(256) void mgemm3_k(const float* __restrict__ A0,
                                                const float* __restrict__ A1,
                                                const float* __restrict__ W,
                                                const float* __restrict__ bias,
                                                float* __restrict__ C,
                                                const float* __restrict__ E,
                                                int N, int K) {
    __shared__ __align__(16) short Ah[64][72];
    __shared__ __align__(16) short Al[64][72];
    __shared__ __align__(16) short Bh[64][72];
    __shared__ __align__(16) short Bl[64][72];
    const int tid = threadIdx.x;
    const int row0 = blockIdx.y * 64, col0 = blockIdx.x * 64;
    const int lane = tid & 63, w = tid >> 6;
    const int rm = (w >> 1) * 32, cn = (w & 1) * 32;
    const int fr = lane & 15, kg = lane >> 4;
    const int ar = tid >> 2, akq = (tid & 3) * 16;
    const int bkk = (tid >> 4) * 4, bnn = (tid & 15) * 4;
    f32x4 acc[2][2] = {};
    for (int k0 = 0; k0 < K; k0 += 64) {
        {
            const float* src;
            if (AMODE == 0) src = A0 + (size_t)(row0 + ar) * K + k0 + akq;
            else {
                int gk = k0 + akq;
                src = (gk < XX) ? (A0 + (size_t)(row0 + ar) * XX + gk)
                                : (A1 + (size_t)(row0 + ar) * HH + (gk - XX));
            }
            short hs[16], ls[16];
            #pragma unroll
            for (int q = 0; q < 4; ++q) {
                float4 v = reinterpret_cast<const float4*>(src)[q];
                float f[4] = {v.x, v.y, v.z, v.w};
                #pragma unroll
                for (int e = 0; e < 4; ++e) {
                    unsigned short hb = f2bf(f[e]);
                    hs[q * 4 + e] = (short)hb;
                    ls[q * 4 + e] = (short)f2bf(f[e] - bf2f(hb));
                }
            }
            *reinterpret_cast<bf16x8*>(&Ah[ar][akq])     = *reinterpret_cast<bf16x8*>(&hs[0]);
            *reinterpret_cast<bf16x8*>(&Ah[ar][akq + 8]) = *reinterpret_cast<bf16x8*>(&hs[8]);
            *reinterpret_cast<bf16x8*>(&Al[ar][akq])     = *reinterpret_cast<bf16x8*>(&ls[0]);
            *reinterpret_cast<bf16x8*>(&Al[ar][akq + 8]) = *reinterpret_cast<bf16x8*>(&ls[8]);
        }
        if (BLAYOUT == 1) {
            const float* src = W + (size_t)(col0 + ar) * K + k0 + akq;
            short hs[16], ls[16];
            #pragma unroll
            for (int q = 0; q < 4; ++q) {
                float4 v = reinterpret_cast<const float4*>(src)[q];
                float f[4] = {v.x, v.y, v.z, v.w};
                #pragma unroll
                for (int e = 0; e < 4; ++e) {
                    unsigned short hb = f2bf(f[e]);
                    hs[q * 4 + e] = (short)hb;
                    ls[q * 4 + e] = (short)f2bf(f[e] - bf2f(hb));
                }
            }
            *reinterpret_cast<bf16x8*>(&Bh[ar][akq])     = *reinterpret_cast<bf16x8*>(&hs[0]);
            *reinterpret_cast<bf16x8*>(&Bh[ar][akq + 8]) = *reinterpret_cast<bf16x8*>(&hs[8]);
            *reinterpret_cast<bf16x8*>(&Bl[ar][akq])     = *reinterpret_cast<bf16x8*>(&ls[0]);
            *reinterpret_cast<bf16x8*>(&Bl[ar][akq + 8]) = *reinterpret_cast<bf16x8*>(&ls[8]);
        } else {
            float4 r0 = *reinterpret_cast<const float4*>(W + (size_t)(k0 + bkk + 0) * N + col0 + bnn);
            float4 r1 = *reinterpret_cast<const float4*>(W + (size_t)(k0 + bkk + 1) * N + col0 + bnn);
            float4 r2 = *reinterpret_cast<const float4*>(W + (size_t)(k0 + bkk + 2) * N + col0 + bnn);
            float4 r3 = *reinterpret_cast<const float4*>(W + (size_t)(k0 + bkk + 3) * N + col0 + bnn);
            float col[4][4] = {{r0.x, r1.x, r2.x, r3.x}, {r0.y, r1.y, r2.y, r3.y},
                               {r0.z, r1.z, r2.z, r3.z}, {r0.w, r1.w, r2.w, r3.w}};
            #pragma unroll
            for (int j = 0; j < 4; ++j) {
                s16x4 hv, lv;
                #pragma unroll
                for (int e = 0; e < 4; ++e) {
                    unsigned short hb = f2bf(col[j][e]);
                    hv[e] = (short)hb;
                    lv[e] = (short)f2bf(col[j][e] - bf2f(hb));
                }
                *reinterpret_cast<s16x4*>(&Bh[bnn + j][bkk]) = hv;
                *reinterpret_cast<s16x4*>(&Bl[bnn + j][bkk]) = lv;
            }
        }
        __syncthreads();
        #pragma unroll
        for (int ks = 0; ks < 64; ks += 32) {
            bf16x8 ah[2], al[2], bh[2], bl[2];
            #pragma unroll
            for (int mf = 0; mf < 2; ++mf) {
                ah[mf] = *reinterpret_cast<const bf16x8*>(&Ah[rm + mf * 16 + fr][ks + kg * 8]);
                al[mf] = *reinterpret_cast<const bf16x8*>(&Al[rm + mf * 16 + fr][ks + kg * 8]);
            }
            #pragma unroll
            for (int nf = 0; nf < 2; ++nf) {
                bh[nf] = *reinterpret_cast<const bf16x8*>(&Bh[cn + nf * 16 + fr][ks + kg * 8]);
                bl[nf] = *reinterpret_cast<const bf16x8*>(&Bl[cn + nf * 16 + fr][ks + kg * 8]);
            }
            #pragma unroll
            for (int mf = 0; mf < 2; ++mf)
                #pragma unroll
                for (int nf = 0; nf < 2; ++nf) {
                    acc[mf][nf] = __builtin_amdgcn_mfma_f32_16x16x32_bf16(ah[mf], bh[nf], acc[mf][nf], 0, 0, 0);
                    acc[mf][nf] = __builtin_amdgcn_mfma_f32_16x16x32_bf16(ah[mf], bl[nf], acc[mf][nf], 0, 0, 0);
                    acc[mf][nf] = __builtin_amdgcn_mfma_f32_16x16x32_bf16(al[mf], bh[nf], acc[mf][nf], 0, 0, 0);
                }
        }
        __syncthreads();
    }
    #pragma unroll
    for (int mf = 0; mf < 2; ++mf)
        #pragma unroll
        for (int nf = 0; nf < 2; ++nf)
            #pragma unroll
            for (int i = 0; i < 4; ++i) {
                int row = row0 + rm + mf * 16 + kg * 4 + i;
                int col = col0 + cn + nf * 16 + fr;
                float v = acc[mf][nf][i] + bias[col];
                if (EPI == 0) C[(size_t)row * N + col] = v;
                else {
                    size_t base = (size_t)row * KCAT + XX + col;
                    C[base] = E[base] * sigm(v);
                }
            }
}

__global__ __launch_bounds__(256) void softmax3_k(float* __restrict__ rh) {
    int b = blockIdx.x;
    float* row = rh + (size_t)b * MM;
    int t = threadIdx.x;
    float v0 = row[t], v1 = row[t + 256];
    float m = fmaxf(v0, v1);
    #pragma unroll
    for (int off = 1; off < 64; off <<= 1) m = fmaxf(m, __shfl_xor(m, off));
    __shared__ float red[8];
    int wid = t >> 6, lane = t & 63;
    if (lane == 0) red[wid] = m;
    __syncthreads();
    float mm = fmaxf(fmaxf(red[0], red[1]), fmaxf(red[2], red[3]));
    float e0 = expf(v0 - mm), e1 = expf(v1 - mm);
    float s = e0 + e1;
    #pragma unroll
    for (int off = 1; off < 64; off <<= 1) s += __shfl_xor(s, off);
    if (lane == 0) red[4 + wid] = s;
    __syncthreads();
    float inv = 1.0f / (red[4] + red[5] + red[6] + red[7]);
    row[t] = e0 * inv;
    row[t + 256] = e1 * inv;
}

__global__ __launch_bounds__(512) void hentry3_k(const float* __restrict__ hidx,
                                                 const float* __restrict__ hmem,
                                                 float* __restrict__ concatb) {
    int b = blockIdx.x;
    int r = threadIdx.x;
    __shared__ float wi[MM];
    wi[r] = hidx[(size_t)b * MM + r];
    __syncthreads();
    const float* hm = hmem + (size_t)b * MM * RR + r;
    float acc = 0.f;
    #pragma unroll 8
    for (int m = 0; m < MM; ++m) acc += wi[m] * hm[(size_t)m * RR];
    concatb[(size_t)b * KCAT + KXC + r] = acc;
}

__global__ __launch_bounds__(256) void lstm3_k(const float* __restrict__ pre,
                                               const float* __restrict__ c,
                                               const float* __restrict__ concatb,
                                               float* __restrict__ out) {
    int idx = blockIdx.x * 256 + threadIdx.x;
    int b = idx / 1536, q = idx - b * 1536;
    const float* p = pre + (size_t)b * NFULL;
    if (q < HH) {
        float iv = p[q], jv = p[HH + q], fv = p[2 * HH + q], ov = p[3 * HH + q];
        float cc = c[(size_t)b * HH + q];
        float nc = tanhf(cc * sigm(fv + 1.0f) + sigm(iv) * tanhf(jv));
        float nh = nc * sigm(ov);
        out[(size_t)b * 1536 + q] = nh;
        out[OFF_NH + (size_t)b * HH + q] = nh;
        out[OFF_NC + (size_t)b * HH + q] = nc;
    } else {
        int r = q - HH;
        float om = p[4 * HH + r];
        float he = concatb[(size_t)b * KCAT + KXC + r];
        out[(size_t)b * 1536 + HH + r] = he * sigm(om);
    }
}

__global__ __launch_bounds__(256) void hmemupd3_k(const float* __restrict__ hmem,
                                                  const float* __restrict__ wval,
                                                  const float* __restrict__ widx,
                                                  float* __restrict__ outhm) {
    size_t n4 = (size_t)BB * MM * RR / 4;
    size_t stride = (size_t)gridDim.x * blockDim.x;
    for (size_t i = (size_t)blockIdx.x * blockDim.x + threadIdx.x; i < n4; i += stride) {
        size_t e = i * 4;
        int r = (int)(e & (RR - 1));
        int m = (int)((e >> 9) & (MM - 1));
        int b = (int)(e >> 18);
        float wi = widx[(size_t)b * MM + m];
        float om = 1.0f - wi;
        float4 hv = *reinterpret_cast<const float4*>(hmem + e);
        float4 wv = *reinterpret_cast<const float4*>(wval + (size_t)b * RR + r);
        float4 o;
        o.x = wv.x * wi + hv.x * om;
        o.y = wv.y * wi + hv.y * om;
        o.z = wv.z * wi + hv.z * om;
        o.w = wv.w * wi + hv.w * om;
        *reinterpret_cast<float4*>(outhm + e) = o;
    }
}

// ===========================================================================
extern "C" void kernel_launch(void* const* d_in, const int* in_sizes, int n_in,
                              void* d_out, int out_size, void* d_ws, size_t ws_size,
                              hipStream_t stream) {
    const float* x      = (const float*)d_in[0];
    const float* c      = (const float*)d_in[2];
    const float* hmem   = (const float*)d_in[3];
    const float* W_full = (const float*)d_in[4];
    const float* bias   = (const float*)d_in[5];
    const float* W_full1= (const float*)d_in[6];
    const float* bias1  = (const float*)d_in[7];
    const float* trans_w= (const float*)d_in[8];
    const float* trans_b= (const float*)d_in[9];
    const float* fc_w   = (const float*)d_in[10];
    const float* fc_b   = (const float*)d_in[11];

    float* out = (float*)d_out;

    // ---- workspace layout (bytes), with liveness-based aliasing
    constexpr size_t SZ_WT   = (size_t)NFULL * KCAT * 2;   // 18,874,368
    constexpr size_t SZ_WT1  = (size_t)NG * KCAT * 2;      //  6,291,456
    constexpr size_t SZ_FCW  = (size_t)MM * KXC * 2;       //  1,572,864
    constexpr size_t SZ_TRW  = (size_t)RR * KXC * 2;       //  1,572,864
    constexpr size_t SZ_CAT  = (size_t)BB * KCAT * 2;      //  1,048,576
    constexpr size_t SZ_XNC  = (size_t)BB * KXC * 2;       //    786,432
    constexpr size_t SZ_RH   = (size_t)BB * MM * 4;        //    524,288
    constexpr size_t SZ_RH6  = 6 * SZ_RH;                  //  3,145,728
    constexpr size_t SZ_GP4  = 4 * (size_t)BB * NG * 4;    //  6,291,456
    constexpr size_t SZ_PRE2 = 2 * (size_t)BB * NFULL * 4; //  9,437,184
    constexpr size_t SZ_WV6  = 6 * SZ_RH;                  //  3,145,728
    // region R1: [wt1 hi|lo, fcw hi|lo, rh6] all dead before big GEMM writes pre2
    constexpr size_t SZ_R1 = 2 * SZ_WT1 + 2 * SZ_FCW + SZ_RH6;  // 18,874,368 >= SZ_PRE2
    // region R2: gpart4 dead before trans writes wval6
    constexpr size_t SZ_R2 = SZ_GP4;                             // >= SZ_WV6
    constexpr size_t NEED = 2 * SZ_WT + 2 * SZ_TRW + 2 * SZ_CAT   // wt, trw, cat+gat
                          + 2 * SZ_CAT                             // (cat uses 2, gat uses 2)
                          + 2 * SZ_XNC + SZ_RH                     // xnc, hidx
                          + SZ_R1 + SZ_R2;                         // ~62.9 MB

    if (ws_size >= NEED) {
        char* p = (char*)d_ws;
        short* wt_hi  = (short*)p; p += SZ_WT;
        short* wt_lo  = (short*)p; p += SZ_WT;
        short* trw_hi = (short*)p; p += SZ_TRW;
        short* trw_lo = (short*)p; p += SZ_TRW;
        short* cat_hi = (short*)p; p += SZ_CAT;
        short* cat_lo = (short*)p; p += SZ_CAT;
        short* gat_hi = (short*)p; p += SZ_CAT;
        short* gat_lo = (short*)p; p += SZ_CAT;
        short* xnc_hi = (short*)p; p += SZ_XNC;
        short* xnc_lo = (short*)p; p += SZ_XNC;
        float* hidx   = (float*)p; p += SZ_RH;
        char*  r1     = p;         p += SZ_R1;
        char*  r2     = p;
        short* wt1_hi = (short*)r1;
        short* wt1_lo = (short*)(r1 + SZ_WT1);
        short* fcw_hi = (short*)(r1 + 2 * SZ_WT1);
        short* fcw_lo = (short*)(r1 + 2 * SZ_WT1 + SZ_FCW);
        float* rh6    = (float*)(r1 + 2 * SZ_WT1 + 2 * SZ_FCW);
        float* pre2   = (float*)r1;        // aliases wt1/fcw/rh6 (dead by then)
        float* gp4    = (float*)r2;
        float* wv6    = (float*)r2;        // aliases gp4 (dead by then)

        // 1-2. weight conversion
        convt_k<<<dim3(KCAT / 64, 96), 256, 0, stream>>>(W_full, wt_hi, wt_lo,
                                                         W_full1, wt1_hi, wt1_lo);
        convw_k<<<dim3(MM * KXC / 8 / 256, 2), 256, 0, stream>>>(fc_w, fcw_hi, fcw_lo,
                                                                 trans_w, trw_hi, trw_lo);
        // 3. activations split
        prep_k<<<BB * KXC / 4 / 256, 256, 0, stream>>>(x, c, cat_hi, cat_lo,
                                                       gat_hi, gat_lo, xnc_hi, xnc_lo);
        // 4. read_head partials (split-K 6)
        mgemm128<<<dim3(MM / 128, BB / 128, 6), 256, 0, stream>>>(
            cat_hi, cat_lo, KCAT, fcw_hi, fcw_lo, KXC, fc_b,
            rh6, MM, (size_t)BB * MM, KXC / 6);
        // 5. softmax + h_entry
        smhe_k<<<BB, 512, 0, stream>>>(rh6, hmem, hidx, cat_hi, cat_lo);
        // 6. gate partials (split-K 4)
        mgemm128<<<dim3(NG / 128, BB / 128, 4), 256, 0, stream>>>(
            cat_hi, cat_lo, KCAT, wt1_hi, wt1_lo, KCAT, bias1,
            gp4, NG, (size_t)BB * NG, KCAT / 4);
        // 7. gate finish -> gat
        gfin_k<<<BB * NG / 256, 256, 0, stream>>>(gp4, cat_hi, cat_lo, gat_hi, gat_lo);
        // 8. pre partials (split-K 2)
        mgemm128<<<dim3(NFULL / 128, BB / 128, 2), 256, 0, stream>>>(
            gat_hi, gat_lo, KCAT, wt_hi, wt_lo, KCAT, bias,
            pre2, NFULL, (size_t)BB * NFULL, KCAT / 2);
        // 9. LSTM elementwise
        lstm_k<<<BB * 1536 / 256, 256, 0, stream>>>(pre2, c, cat_hi, cat_lo,
                                                    out, xnc_hi, xnc_lo);
        // 10. w_val partials (split-K 6)
        mgemm128<<<dim3(RR / 128, BB / 128, 6), 256, 0, stream>>>(
            xnc_hi, xnc_lo, KXC, trw_hi, trw_lo, KXC, trans_b,
            wv6, RR, (size_t)BB * RR, KXC / 6);
        // 11. hmem blend
        hmemupd_k<<<4096, 256, 0, stream>>>(hmem, wv6, hidx, out + OFF_HM);
    } else {
        // -------- fallback: round-3 path (~10 MB ws) --------
        float* ws      = (float*)d_ws;
        float* hidx    = ws;
        float* concatb = hidx + BB * MM;
        float* gated   = concatb + BB * KCAT;
        float* pre     = gated + BB * KCAT;
        float* wval    = pre + BB * NFULL;
        float* new_c   = out + OFF_NC;

        prep3_k<<<BB * KXC / 256, 256, 0, stream>>>(x, c, concatb, gated);
        mgemm3_k<1, 1, 0><<<dim3(MM / 64, BB / 64), 256, 0, stream>>>(
            x, c, fc_w, fc_b, hidx, nullptr, MM, KXC);
        softmax3_k<<<BB, 256, 0, stream>>>(hidx);
        hentry3_k<<<BB, 512, 0, stream>>>(hidx, hmem, concatb);
        mgemm3_k<0, 0, 1><<<dim3(NG / 64, BB / 64), 256, 0, stream>>>(
            concatb, nullptr, W_full1, bias1, gated, concatb, NG, KCAT);
        mgemm3_k<0, 0, 0><<<dim3(NFULL / 64, BB / 64), 256, 0, stream>>>(
            gated, nullptr, W_full, bias, pre, nullptr, NFULL, KCAT);
        lstm3_k<<<BB * 1536 / 256, 256, 0, stream>>>(pre, c, concatb, out);
        mgemm3_k<1, 1, 0><<<dim3(RR / 64, BB / 64), 256, 0, stream>>>(
            x, new_c, trans_w, trans_b, wval, nullptr, RR, KXC);
        hmemupd3_k<<<4096, 256, 0, stream>>>(hmem, wval, hidx, out + OFF_HM);
    }
}

// Round 6
// 401.981 us; speedup vs baseline: 1.2689x; 1.2689x over previous
//
#include <hip/hip_runtime.h>
#include <hip/hip_bf16.h>
#include <cstddef>

// Problem constants
#define BB 256
#define XX 512
#define HH 1024
#define RR 512
#define MM 512
// derived
#define KCAT 2048          // X + H + R
#define KXC 1536           // X + H
#define NFULL 4608         // R + 4H
#define NG 1536            // R + H

// d_out offsets (floats)
#define OFF_NH (BB*1536)
#define OFF_NC (OFF_NH + BB*HH)
#define OFF_HM (OFF_NC + BB*HH)

typedef __attribute__((ext_vector_type(8))) short bf16x8;
typedef __attribute__((ext_vector_type(4))) short s16x4;
typedef __attribute__((ext_vector_type(4))) float f32x4;

__device__ __forceinline__ float sigm(float x) { return 1.0f / (1.0f + expf(-x)); }

__device__ __forceinline__ unsigned short f2bf(float f) {
    unsigned u = __float_as_uint(f);
    u = u + 0x7fffu + ((u >> 16) & 1u);
    return (unsigned short)(u >> 16);
}
__device__ __forceinline__ float bf2f(unsigned short h) {
    return __uint_as_float((unsigned)h << 16);
}

// ===========================================================================
// ===============            MAIN (pre-split) PATH            ===============
// ===========================================================================

// Straight convert: src [n] f32 -> hi/lo bf16 (same layout). 8 elems/thread.
__global__ __launch_bounds__(256) void convw_k(const float* __restrict__ src,
                                               short* __restrict__ hi,
                                               short* __restrict__ lo) {
    size_t e0 = ((size_t)blockIdx.x * 256 + threadIdx.x) * 8;
    short hs[8], ls[8];
    #pragma unroll
    for (int q = 0; q < 2; ++q) {
        float4 v = reinterpret_cast<const float4*>(src + e0)[q];
        float f[4] = {v.x, v.y, v.z, v.w};
        #pragma unroll
        for (int e = 0; e < 4; ++e) {
            unsigned short hb = f2bf(f[e]);
            hs[q * 4 + e] = (short)hb;
            ls[q * 4 + e] = (short)f2bf(f[e] - bf2f(hb));
        }
    }
    *reinterpret_cast<bf16x8*>(hi + e0) = *reinterpret_cast<bf16x8*>(&hs[0]);
    *reinterpret_cast<bf16x8*>(lo + e0) = *reinterpret_cast<bf16x8*>(&ls[0]);
}

// Transpose-convert both NN weights in one launch.
// grid (KCAT/64=32, 72+24=96): by<72 -> W_full [2048][4608], else W_full1 [2048][1536].
__global__ __launch_bounds__(256) void convt_k(const float* __restrict__ W0,
                                               short* __restrict__ T0hi, short* __restrict__ T0lo,
                                               const float* __restrict__ W1,
                                               short* __restrict__ T1hi, short* __restrict__ T1lo) {
    __shared__ __align__(16) short lh[64][72];
    __shared__ __align__(16) short ll[64][72];
    const int tid = threadIdx.x;
    const int by = blockIdx.y;
    const float* W;
    short *Thi, *Tlo;
    int Ndim, n0;
    if (by < 72) { W = W0; Thi = T0hi; Tlo = T0lo; Ndim = NFULL; n0 = by * 64; }
    else         { W = W1; Thi = T1hi; Tlo = T1lo; Ndim = NG;    n0 = (by - 72) * 64; }
    const int k0 = blockIdx.x * 64;
    {
        int kr = (tid >> 4) * 4;
        int nc = (tid & 15) * 4;
        #pragma unroll
        for (int i = 0; i < 4; ++i) {
            float4 v = *reinterpret_cast<const float4*>(W + (size_t)(k0 + kr + i) * Ndim + n0 + nc);
            float f[4] = {v.x, v.y, v.z, v.w};
            #pragma unroll
            for (int e = 0; e < 4; ++e) {
                unsigned short hb = f2bf(f[e]);
                lh[nc + e][kr + i] = (short)hb;
                ll[nc + e][kr + i] = (short)f2bf(f[e] - bf2f(hb));
            }
        }
    }
    __syncthreads();
    {
        int nl = tid >> 2;
        int kq = (tid & 3) * 16;
        size_t base = (size_t)(n0 + nl) * KCAT + k0 + kq;
        *reinterpret_cast<bf16x8*>(Thi + base)     = *reinterpret_cast<const bf16x8*>(&lh[nl][kq]);
        *reinterpret_cast<bf16x8*>(Thi + base + 8) = *reinterpret_cast<const bf16x8*>(&lh[nl][kq + 8]);
        *reinterpret_cast<bf16x8*>(Tlo + base)     = *reinterpret_cast<const bf16x8*>(&ll[nl][kq]);
        *reinterpret_cast<bf16x8*>(Tlo + base + 8) = *reinterpret_cast<const bf16x8*>(&ll[nl][kq + 8]);
    }
}

// prep: cat[:,0:1536] = split([x | c])
__global__ __launch_bounds__(256) void prep_k(const float* __restrict__ x,
                                              const float* __restrict__ c,
                                              short* __restrict__ cat_hi,
                                              short* __restrict__ cat_lo) {
    int i = blockIdx.x * 256 + threadIdx.x;       // B*1536/4 threads
    int e0 = i * 4;
    int b = e0 / KXC, q = e0 - b * KXC;
    float4 v = (q < XX) ? *reinterpret_cast<const float4*>(x + (size_t)b * XX + q)
                        : *reinterpret_cast<const float4*>(c + (size_t)b * HH + (q - XX));
    float f[4] = {v.x, v.y, v.z, v.w};
    s16x4 hv, lv;
    #pragma unroll
    for (int e = 0; e < 4; ++e) {
        unsigned short hb = f2bf(f[e]);
        hv[e] = (short)hb;
        lv[e] = (short)f2bf(f[e] - bf2f(hb));
    }
    *reinterpret_cast<s16x4*>(cat_hi + (size_t)b * KCAT + q) = hv;
    *reinterpret_cast<s16x4*>(cat_lo + (size_t)b * KCAT + q) = lv;
}

// ---------------------------------------------------------------------------
// mgemm_k: 64(row)x128(col) tile, BK=64, 4 waves (2x2), wave-tile 32x64
// (2x4 frags of 16x16x32), reg-prefetch double buffer, hi/lo 3-pass.
// A: [row][lda0] (GATHER=1: k<512 -> A0, k>=512 -> A1[row][lda1], idx k-512)
// B: [n][ldb] (pre-transposed). Split-K via blockIdx.z: writes raw partial
// to Cbase + z*chunk_stride; bias added only by chunk 0.
template<int GATHER>
__global__ __launch_bounds__(256, 2) void mgemm_k(const short* __restrict__ A0h,
                                                  const short* __restrict__ A0l, int lda0,
                                                  const short* __restrict__ A1h,
                                                  const short* __restrict__ A1l, int lda1,
                                                  const short* __restrict__ Bh_,
                                                  const short* __restrict__ Bl_, int ldb,
                                                  const float* __restrict__ bias,
                                                  float* __restrict__ Cbase, int ldc,
                                                  size_t chunk_stride, int kchunk) {
    __shared__ __align__(16) short Ah[64][72];
    __shared__ __align__(16) short Al[64][72];
    __shared__ __align__(16) short Bh[128][72];
    __shared__ __align__(16) short Bl[128][72];

    const int tid = threadIdx.x;
    const int col0 = blockIdx.x * 128;
    const int row0 = blockIdx.y * 64;
    const int z = blockIdx.z;
    const int kbeg = z * kchunk;
    float* C = Cbase + (size_t)z * chunk_stride;

    const int lane = tid & 63, w = tid >> 6;
    const int rm = (w >> 1) * 32, cn = (w & 1) * 64;
    const int fr = lane & 15, kg = lane >> 4;

    const int ar = tid >> 2, akq = (tid & 3) * 16;   // A stage: 32 B/thread
    const int br = tid >> 1, bkq = (tid & 1) * 32;   // B stage: 64 B/thread

    f32x4 acc[2][4] = {};
    int4 pa[4], pb[8];

    const short* bHrow = Bh_ + (size_t)(col0 + br) * ldb + bkq;
    const short* bLrow = Bl_ + (size_t)(col0 + br) * ldb + bkq;

    const int steps = kchunk >> 6;

    // prologue load (tile 0)
    {
        int gk = kbeg + akq;
        const short* ah_ = (GATHER && gk >= XX) ? A1h + (size_t)(row0 + ar) * lda1 + (gk - XX)
                                                : A0h + (size_t)(row0 + ar) * lda0 + gk;
        const short* al_ = (GATHER && gk >= XX) ? A1l + (size_t)(row0 + ar) * lda1 + (gk - XX)
                                                : A0l + (size_t)(row0 + ar) * lda0 + gk;
        pa[0] = *reinterpret_cast<const int4*>(ah_);
        pa[1] = *reinterpret_cast<const int4*>(ah_ + 8);
        pa[2] = *reinterpret_cast<const int4*>(al_);
        pa[3] = *reinterpret_cast<const int4*>(al_ + 8);
        #pragma unroll
        for (int j = 0; j < 4; ++j) {
            pb[j]     = *reinterpret_cast<const int4*>(bHrow + kbeg + j * 8);
            pb[4 + j] = *reinterpret_cast<const int4*>(bLrow + kbeg + j * 8);
        }
    }

    for (int t = 0; t < steps; ++t) {
        // write staged regs to LDS
        *reinterpret_cast<int4*>(&Ah[ar][akq])     = pa[0];
        *reinterpret_cast<int4*>(&Ah[ar][akq + 8]) = pa[1];
        *reinterpret_cast<int4*>(&Al[ar][akq])     = pa[2];
        *reinterpret_cast<int4*>(&Al[ar][akq + 8]) = pa[3];
        #pragma unroll
        for (int j = 0; j < 4; ++j) {
            *reinterpret_cast<int4*>(&Bh[br][bkq + j * 8]) = pb[j];
            *reinterpret_cast<int4*>(&Bl[br][bkq + j * 8]) = pb[4 + j];
        }
        __syncthreads();
        // issue next tile's loads; latency hides under MFMA phase
        if (t + 1 < steps) {
            int kc = kbeg + (t + 1) * 64;
            int gk = kc + akq;
            const short* ah_ = (GATHER && gk >= XX) ? A1h + (size_t)(row0 + ar) * lda1 + (gk - XX)
                                                    : A0h + (size_t)(row0 + ar) * lda0 + gk;
            const short* al_ = (GATHER && gk >= XX) ? A1l + (size_t)(row0 + ar) * lda1 + (gk - XX)
                                                    : A0l + (size_t)(row0 + ar) * lda0 + gk;
            pa[0] = *reinterpret_cast<const int4*>(ah_);
            pa[1] = *reinterpret_cast<const int4*>(ah_ + 8);
            pa[2] = *reinterpret_cast<const int4*>(al_);
            pa[3] = *reinterpret_cast<const int4*>(al_ + 8);
            #pragma unroll
            for (int j = 0; j < 4; ++j) {
                pb[j]     = *reinterpret_cast<const int4*>(bHrow + kc + j * 8);
                pb[4 + j] = *reinterpret_cast<const int4*>(bLrow + kc + j * 8);
            }
        }
        // MFMA phase
        #pragma unroll
        for (int ks = 0; ks < 64; ks += 32) {
            bf16x8 ah2[2], al2[2], bh4[4], bl4[4];
            #pragma unroll
            for (int mf = 0; mf < 2; ++mf) {
                ah2[mf] = *reinterpret_cast<const bf16x8*>(&Ah[rm + mf * 16 + fr][ks + kg * 8]);
                al2[mf] = *reinterpret_cast<const bf16x8*>(&Al[rm + mf * 16 + fr][ks + kg * 8]);
            }
            #pragma unroll
            for (int nf = 0; nf < 4; ++nf) {
                bh4[nf] = *reinterpret_cast<const bf16x8*>(&Bh[cn + nf * 16 + fr][ks + kg * 8]);
                bl4[nf] = *reinterpret_cast<const bf16x8*>(&Bl[cn + nf * 16 + fr][ks + kg * 8]);
            }
            #pragma unroll
            for (int mf = 0; mf < 2; ++mf)
                #pragma unroll
                for (int nf = 0; nf < 4; ++nf) {
                    acc[mf][nf] = __builtin_amdgcn_mfma_f32_16x16x32_bf16(ah2[mf], bh4[nf], acc[mf][nf], 0, 0, 0);
                    acc[mf][nf] = __builtin_amdgcn_mfma_f32_16x16x32_bf16(ah2[mf], bl4[nf], acc[mf][nf], 0, 0, 0);
                    acc[mf][nf] = __builtin_amdgcn_mfma_f32_16x16x32_bf16(al2[mf], bh4[nf], acc[mf][nf], 0, 0, 0);
                }
        }
        __syncthreads();
    }

    // epilogue: C/D layout col=lane&15, row=(lane>>4)*4+i
    #pragma unroll
    for (int mf = 0; mf < 2; ++mf)
        #pragma unroll
        for (int nf = 0; nf < 4; ++nf)
            #pragma unroll
            for (int i = 0; i < 4; ++i) {
                int row = row0 + rm + mf * 16 + kg * 4 + i;
                int col = col0 + cn + nf * 16 + fr;
                float v = acc[mf][nf][i];
                if (z == 0) v += bias[col];
                C[(size_t)row * ldc + col] = v;
            }
}

// softmax over summed fc partials (6) -> hidx. block b, 512 threads.
__global__ __launch_bounds__(512) void smax_k(const float* __restrict__ rhp,
                                              float* __restrict__ hidx) {
    __shared__ float red[8];
    __shared__ float red2[8];
    int b = blockIdx.x, t = threadIdx.x;
    float v = 0.f;
    #pragma unroll
    for (int zz = 0; zz < 6; ++zz) v += rhp[(size_t)zz * (BB * MM) + (size_t)b * MM + t];
    float m = v;
    #pragma unroll
    for (int off = 1; off < 64; off <<= 1) m = fmaxf(m, __shfl_xor(m, off));
    int wid = t >> 6, lane = t & 63;
    if (lane == 0) red[wid] = m;
    __syncthreads();
    float mm = red[0];
    #pragma unroll
    for (int i = 1; i < 8; ++i) mm = fmaxf(mm, red[i]);
    float e = expf(v - mm);
    float s = e;
    #pragma unroll
    for (int off = 1; off < 64; off <<= 1) s += __shfl_xor(s, off);
    if (lane == 0) red2[wid] = s;
    __syncthreads();
    float tot = red2[0];
    #pragma unroll
    for (int i = 1; i < 8; ++i) tot += red2[i];
    hidx[(size_t)b * MM + t] = e / tot;
}

// h_entry partial: block (b,s) sums m in [s*128,(s+1)*128)
__global__ __launch_bounds__(512) void hepart_k(const float* __restrict__ hidx,
                                                const float* __restrict__ hmem,
                                                float* __restrict__ hep) {
    __shared__ float wi[128];
    int b = blockIdx.x, s = blockIdx.y, t = threadIdx.x;
    if (t < 128) wi[t] = hidx[(size_t)b * MM + s * 128 + t];
    __syncthreads();
    const float* hm = hmem + ((size_t)b * MM + (size_t)s * 128) * RR + t;
    float acc = 0.f;
    #pragma unroll 8
    for (int j = 0; j < 128; ++j) acc += wi[j] * hm[(size_t)j * RR];
    hep[((size_t)s * BB + b) * RR + t] = acc;
}

// h_entry finish: sum 4 partials, split into cat[:,1536:2048]
__global__ __launch_bounds__(256) void hefin_k(const float* __restrict__ hep,
                                               short* __restrict__ cat_hi,
                                               short* __restrict__ cat_lo) {
    int i = blockIdx.x * 256 + threadIdx.x;     // B*512
    int b = i >> 9, r = i & (RR - 1);
    float acc = 0.f;
    #pragma unroll
    for (int s = 0; s < 4; ++s) acc += hep[((size_t)s * BB + b) * RR + r];
    size_t base = (size_t)b * KCAT + KXC + r;
    unsigned short hb = f2bf(acc);
    cat_hi[base] = (short)hb;
    cat_lo[base] = (short)f2bf(acc - bf2f(hb));
}

// gate finish: g = sigm(sum of 4 partials); gatg = split(cat[:,512:]*g)
__global__ __launch_bounds__(256) void gfin_k(const float* __restrict__ gp,
                                              const short* __restrict__ cat_hi,
                                              const short* __restrict__ cat_lo,
                                              short* __restrict__ gatg_hi,
                                              short* __restrict__ gatg_lo) {
    int i = blockIdx.x * 256 + threadIdx.x;     // B*1536
    int b = i / NG, q = i - b * NG;
    float s = 0.f;
    #pragma unroll
    for (int zz = 0; zz < 4; ++zz) s += gp[(size_t)zz * (BB * NG) + (size_t)b * NG + q];
    size_t base = (size_t)b * KCAT + XX + q;
    float e = bf2f((unsigned short)cat_hi[base]) + bf2f((unsigned short)cat_lo[base]);
    float gv = e * sigm(s);
    unsigned short hb = f2bf(gv);
    gatg_hi[(size_t)b * NG + q] = (short)hb;
    gatg_lo[(size_t)b * NG + q] = (short)f2bf(gv - bf2f(hb));
}

// LSTM elementwise; sums 2 big-GEMM partials; writes outputs + ncg=split(new_c)
__global__ __launch_bounds__(256) void lstm_k(const float* __restrict__ pre0,
                                              const float* __restrict__ c,
                                              const short* __restrict__ cat_hi,
                                              const short* __restrict__ cat_lo,
                                              float* __restrict__ out,
                                              short* __restrict__ ncg_hi,
                                              short* __restrict__ ncg_lo) {
    const float* pre1 = pre0 + (size_t)BB * NFULL;
    int idx = blockIdx.x * 256 + threadIdx.x;   // B*1536
    int b = idx / 1536, q = idx - b * 1536;
    size_t pb = (size_t)b * NFULL;
    if (q < HH) {
        float iv = pre0[pb + q] + pre1[pb + q];
        float jv = pre0[pb + HH + q] + pre1[pb + HH + q];
        float fv = pre0[pb + 2 * HH + q] + pre1[pb + 2 * HH + q];
        float ov = pre0[pb + 3 * HH + q] + pre1[pb + 3 * HH + q];
        float cc = c[(size_t)b * HH + q];
        float nc = tanhf(cc * sigm(fv + 1.0f) + sigm(iv) * tanhf(jv));
        float nh = nc * sigm(ov);
        out[(size_t)b * 1536 + q] = nh;
        out[OFF_NH + (size_t)b * HH + q] = nh;
        out[OFF_NC + (size_t)b * HH + q] = nc;
        unsigned short hb = f2bf(nc);
        ncg_hi[(size_t)b * HH + q] = (short)hb;
        ncg_lo[(size_t)b * HH + q] = (short)f2bf(nc - bf2f(hb));
    } else {
        int r = q - HH;
        float om = pre0[pb + 4 * HH + r] + pre1[pb + 4 * HH + r];
        size_t base = (size_t)b * KCAT + KXC + r;
        float he = bf2f((unsigned short)cat_hi[base]) + bf2f((unsigned short)cat_lo[base]);
        out[(size_t)b * 1536 + HH + r] = he * sigm(om);
    }
}

// reduce 6 w_val partials -> compact wval
__global__ __launch_bounds__(256) void wvred_k(const float* __restrict__ wvp,
                                               float* __restrict__ wval) {
    int i = blockIdx.x * 256 + threadIdx.x;     // B*R/4 float4s
    size_t e = (size_t)i * 4;
    float4 acc = {0.f, 0.f, 0.f, 0.f};
    #pragma unroll
    for (int zz = 0; zz < 6; ++zz) {
        float4 p = *reinterpret_cast<const float4*>(wvp + (size_t)zz * (BB * RR) + e);
        acc.x += p.x; acc.y += p.y; acc.z += p.z; acc.w += p.w;
    }
    *reinterpret_cast<float4*>(wval + e) = acc;
}

// new_hmem blend (single compact wval read — round-4 form)
__global__ __launch_bounds__(256) void hmemupd_k(const float* __restrict__ hmem,
                                                 const float* __restrict__ wval,
                                                 const float* __restrict__ widx,
                                                 float* __restrict__ outhm) {
    size_t n4 = (size_t)BB * MM * RR / 4;
    size_t stride = (size_t)gridDim.x * blockDim.x;
    for (size_t i = (size_t)blockIdx.x * blockDim.x + threadIdx.x; i < n4; i += stride) {
        size_t e = i * 4;
        int r = (int)(e & (RR - 1));
        int m = (int)((e >> 9) & (MM - 1));
        int b = (int)(e >> 18);
        float wi = widx[(size_t)b * MM + m];
        float om = 1.0f - wi;
        float4 hv = *reinterpret_cast<const float4*>(hmem + e);
        float4 wv = *reinterpret_cast<const float4*>(wval + (size_t)b * RR + r);
        float4 o;
        o.x = wv.x * wi + hv.x * om;
        o.y = wv.y * wi + hv.y * om;
        o.z = wv.z * wi + hv.z * om;
        o.w = wv.w * wi + hv.w * om;
        *reinterpret_cast<float4*>(outhm + e) = o;
    }
}

// ===========================================================================
// ===============     FALLBACK (round-3, split-in-loop)       ===============
// ===========================================================================

__global__ __launch_bounds__(256) void prep3_k(const float* __restrict__ x,
                                               const float* __restrict__ c,
                                               float* __restrict__ concatb,
                                               float* __restrict__ gated) {
    int idx = blockIdx.x * 256 + threadIdx.x;
    int b = idx / KXC, q = idx - b * KXC;
    float v;
    if (q < XX) { v = x[b * XX + q]; gated[(size_t)b * KCAT + q] = v; }
    else v = c[b * HH + (q - XX)];
    concatb[(size_t)b * KCAT + q] = v;
}

template<int AMODE, int BLAYOUT, int EPI>
__global__ __launch_bounds__(256) void mgemm3_k(const float* __restrict__ A0,
                                                const float* __restrict__ A1,
                                                const float* __restrict__ W,
                                                const float* __restrict__ bias,
                                                float* __restrict__ C,
                                                const float* __restrict__ E,
                                                int N, int K) {
    __shared__ __align__(16) short Ah[64][72];
    __shared__ __align__(16) short Al[64][72];
    __shared__ __align__(16) short Bh[64][72];
    __shared__ __align__(16) short Bl[64][72];
    const int tid = threadIdx.x;
    const int row0 = blockIdx.y * 64, col0 = blockIdx.x * 64;
    const int lane = tid & 63, w = tid >> 6;
    const int rm = (w >> 1) * 32, cn = (w & 1) * 32;
    const int fr = lane & 15, kg = lane >> 4;
    const int ar = tid >> 2, akq = (tid & 3) * 16;
    const int bkk = (tid >> 4) * 4, bnn = (tid & 15) * 4;
    f32x4 acc[2][2] = {};
    for (int k0 = 0; k0 < K; k0 += 64) {
        {
            const float* src;
            if (AMODE == 0) src = A0 + (size_t)(row0 + ar) * K + k0 + akq;
            else {
                int gk = k0 + akq;
                src = (gk < XX) ? (A0 + (size_t)(row0 + ar) * XX + gk)
                                : (A1 + (size_t)(row0 + ar) * HH + (gk - XX));
            }
            short hs[16], ls[16];
            #pragma unroll
            for (int q = 0; q < 4; ++q) {
                float4 v = reinterpret_cast<const float4*>(src)[q];
                float f[4] = {v.x, v.y, v.z, v.w};
                #pragma unroll
                for (int e = 0; e < 4; ++e) {
                    unsigned short hb = f2bf(f[e]);
                    hs[q * 4 + e] = (short)hb;
                    ls[q * 4 + e] = (short)f2bf(f[e] - bf2f(hb));
                }
            }
            *reinterpret_cast<bf16x8*>(&Ah[ar][akq])     = *reinterpret_cast<bf16x8*>(&hs[0]);
            *reinterpret_cast<bf16x8*>(&Ah[ar][akq + 8]) = *reinterpret_cast<bf16x8*>(&hs[8]);
            *reinterpret_cast<bf16x8*>(&Al[ar][akq])     = *reinterpret_cast<bf16x8*>(&ls[0]);
            *reinterpret_cast<bf16x8*>(&Al[ar][akq + 8]) = *reinterpret_cast<bf16x8*>(&ls[8]);
        }
        if (BLAYOUT == 1) {
            const float* src = W + (size_t)(col0 + ar) * K + k0 + akq;
            short hs[16], ls[16];
            #pragma unroll
            for (int q = 0; q < 4; ++q) {
                float4 v = reinterpret_cast<const float4*>(src)[q];
                float f[4] = {v.x, v.y, v.z, v.w};
                #pragma unroll
                for (int e = 0; e < 4; ++e) {
                    unsigned short hb = f2bf(f[e]);
                    hs[q * 4 + e] = (short)hb;
                    ls[q * 4 + e] = (short)f2bf(f[e] - bf2f(hb));
                }
            }
            *reinterpret_cast<bf16x8*>(&Bh[ar][akq])     = *reinterpret_cast<bf16x8*>(&hs[0]);
            *reinterpret_cast<bf16x8*>(&Bh[ar][akq + 8]) = *reinterpret_cast<bf16x8*>(&hs[8]);
            *reinterpret_cast<bf16x8*>(&Bl[ar][akq])     = *reinterpret_cast<bf16x8*>(&ls[0]);
            *reinterpret_cast<bf16x8*>(&Bl[ar][akq + 8]) = *reinterpret_cast<bf16x8*>(&ls[8]);
        } else {
            float4 r0 = *reinterpret_cast<const float4*>(W + (size_t)(k0 + bkk + 0) * N + col0 + bnn);
            float4 r1 = *reinterpret_cast<const float4*>(W + (size_t)(k0 + bkk + 1) * N + col0 + bnn);
            float4 r2 = *reinterpret_cast<const float4*>(W + (size_t)(k0 + bkk + 2) * N + col0 + bnn);
            float4 r3 = *reinterpret_cast<const float4*>(W + (size_t)(k0 + bkk + 3) * N + col0 + bnn);
            float col[4][4] = {{r0.x, r1.x, r2.x, r3.x}, {r0.y, r1.y, r2.y, r3.y},
                               {r0.z, r1.z, r2.z, r3.z}, {r0.w, r1.w, r2.w, r3.w}};
            #pragma unroll
            for (int j = 0; j < 4; ++j) {
                s16x4 hv, lv;
                #pragma unroll
                for (int e = 0; e < 4; ++e) {
                    unsigned short hb = f2bf(col[j][e]);
                    hv[e] = (short)hb;
                    lv[e] = (short)f2bf(col[j][e] - bf2f(hb));
                }
                *reinterpret_cast<s16x4*>(&Bh[bnn + j][bkk]) = hv;
                *reinterpret_cast<s16x4*>(&Bl[bnn + j][bkk]) = lv;
            }
        }
        __syncthreads();
        #pragma unroll
        for (int ks = 0; ks < 64; ks += 32) {
            bf16x8 ah[2], al[2], bh[2], bl[2];
            #pragma unroll
            for (int mf = 0; mf < 2; ++mf) {
                ah[mf] = *reinterpret_cast<const bf16x8*>(&Ah[rm + mf * 16 + fr][ks + kg * 8]);
                al[mf] = *reinterpret_cast<const bf16x8*>(&Al[rm + mf * 16 + fr][ks + kg * 8]);
            }
            #pragma unroll
            for (int nf = 0; nf < 2; ++nf) {
                bh[nf] = *reinterpret_cast<const bf16x8*>(&Bh[cn + nf * 16 + fr][ks + kg * 8]);
                bl[nf] = *reinterpret_cast<const bf16x8*>(&Bl[cn + nf * 16 + fr][ks + kg * 8]);
            }
            #pragma unroll
            for (int mf = 0; mf < 2; ++mf)
                #pragma unroll
                for (int nf = 0; nf < 2; ++nf) {
                    acc[mf][nf] = __builtin_amdgcn_mfma_f32_16x16x32_bf16(ah[mf], bh[nf], acc[mf][nf], 0, 0, 0);
                    acc[mf][nf] = __builtin_amdgcn_mfma_f32_16x16x32_bf16(ah[mf], bl[nf], acc[mf][nf], 0, 0, 0);
                    acc[mf][nf] = __builtin_amdgcn_mfma_f32_16x16x32_bf16(al[mf], bh[nf], acc[mf][nf], 0, 0, 0);
                }
        }
        __syncthreads();
    }
    #pragma unroll
    for (int mf = 0; mf < 2; ++mf)
        #pragma unroll
        for (int nf = 0; nf < 2; ++nf)
            #pragma unroll
            for (int i = 0; i < 4; ++i) {
                int row = row0 + rm + mf * 16 + kg * 4 + i;
                int col = col0 + cn + nf * 16 + fr;
                float v = acc[mf][nf][i] + bias[col];
                if (EPI == 0) C[(size_t)row * N + col] = v;
                else {
                    size_t base = (size_t)row * KCAT + XX + col;
                    C[base] = E[base] * sigm(v);
                }
            }
}

__global__ __launch_bounds__(256) void softmax3_k(float* __restrict__ rh) {
    int b = blockIdx.x;
    float* row = rh + (size_t)b * MM;
    int t = threadIdx.x;
    float v0 = row[t], v1 = row[t + 256];
    float m = fmaxf(v0, v1);
    #pragma unroll
    for (int off = 1; off < 64; off <<= 1) m = fmaxf(m, __shfl_xor(m, off));
    __shared__ float red[8];
    int wid = t >> 6, lane = t & 63;
    if (lane == 0) red[wid] = m;
    __syncthreads();
    float mm = fmaxf(fmaxf(red[0], red[1]), fmaxf(red[2], red[3]));
    float e0 = expf(v0 - mm), e1 = expf(v1 - mm);
    float s = e0 + e1;
    #pragma unroll
    for (int off = 1; off < 64; off <<= 1) s += __shfl_xor(s, off);
    if (lane == 0) red[4 + wid] = s;
    __syncthreads();
    float inv = 1.0f / (red[4] + red[5] + red[6] + red[7]);
    row[t] = e0 * inv;
    row[t + 256] = e1 * inv;
}

__global__ __launch_bounds__(512) void hentry3_k(const float* __restrict__ hidx,
                                                 const float* __restrict__ hmem,
                                                 float* __restrict__ concatb) {
    int b = blockIdx.x;
    int r = threadIdx.x;
    __shared__ float wi[MM];
    wi[r] = hidx[(size_t)b * MM + r];
    __syncthreads();
    const float* hm = hmem + (size_t)b * MM * RR + r;
    float acc = 0.f;
    #pragma unroll 8
    for (int m = 0; m < MM; ++m) acc += wi[m] * hm[(size_t)m * RR];
    concatb[(size_t)b * KCAT + KXC + r] = acc;
}

__global__ __launch_bounds__(256) void lstm3_k(const float* __restrict__ pre,
                                               const float* __restrict__ c,
                                               const float* __restrict__ concatb,
                                               float* __restrict__ out) {
    int idx = blockIdx.x * 256 + threadIdx.x;
    int b = idx / 1536, q = idx - b * 1536;
    const float* p = pre + (size_t)b * NFULL;
    if (q < HH) {
        float iv = p[q], jv = p[HH + q], fv = p[2 * HH + q], ov = p[3 * HH + q];
        float cc = c[(size_t)b * HH + q];
        float nc = tanhf(cc * sigm(fv + 1.0f) + sigm(iv) * tanhf(jv));
        float nh = nc * sigm(ov);
        out[(size_t)b * 1536 + q] = nh;
        out[OFF_NH + (size_t)b * HH + q] = nh;
        out[OFF_NC + (size_t)b * HH + q] = nc;
    } else {
        int r = q - HH;
        float om = p[4 * HH + r];
        float he = concatb[(size_t)b * KCAT + KXC + r];
        out[(size_t)b * 1536 + HH + r] = he * sigm(om);
    }
}

// ===========================================================================
extern "C" void kernel_launch(void* const* d_in, const int* in_sizes, int n_in,
                              void* d_out, int out_size, void* d_ws, size_t ws_size,
                              hipStream_t stream) {
    const float* x      = (const float*)d_in[0];
    const float* c      = (const float*)d_in[2];
    const float* hmem   = (const float*)d_in[3];
    const float* W_full = (const float*)d_in[4];
    const float* bias   = (const float*)d_in[5];
    const float* W_full1= (const float*)d_in[6];
    const float* bias1  = (const float*)d_in[7];
    const float* trans_w= (const float*)d_in[8];
    const float* trans_b= (const float*)d_in[9];
    const float* fc_w   = (const float*)d_in[10];
    const float* fc_b   = (const float*)d_in[11];

    float* out = (float*)d_out;

    // ---- workspace layout (bytes), liveness-aliased
    constexpr size_t SZ_WT    = (size_t)NFULL * KCAT * 2;   // 18,874,368 (x2)
    constexpr size_t SZ_WT1   = (size_t)NG * KCAT * 2;      //  6,291,456 (x2)
    constexpr size_t SZ_FCW   = (size_t)MM * KXC * 2;       //  1,572,864 (x2)
    constexpr size_t SZ_CAT   = (size_t)BB * KCAT * 2;      //  1,048,576 (x2)
    constexpr size_t SZ_GATG  = (size_t)BB * NG * 2;        //    786,432 (x2)
    constexpr size_t SZ_NCG   = (size_t)BB * HH * 2;        //    524,288 (x2)
    constexpr size_t SZ_HIDX  = (size_t)BB * MM * 4;        //    524,288
    constexpr size_t SZ_RH6   = 6 * (size_t)BB * MM * 4;    //  3,145,728
    constexpr size_t SZ_HEP   = 4 * (size_t)BB * RR * 4;    //  2,097,152
    constexpr size_t SZ_GP4   = 4 * (size_t)BB * NG * 4;    //  6,291,456
    constexpr size_t SZ_PRE2  = 2 * (size_t)BB * NFULL * 4; //  9,437,184
    constexpr size_t SZ_WV6   = 6 * (size_t)BB * RR * 4;    //  3,145,728
    constexpr size_t SZ_WVAL  = (size_t)BB * RR * 4;        //    524,288
    // wt1 region also hosts wv6+wval later (wt1 dead after gate GEMM)
    constexpr size_t SZ_WT1R  = 2 * SZ_WT1;                 // 12,582,912 >= WV6+WVAL
    // fcw region also hosts trw later (fcw dead after fc GEMM)
    constexpr size_t SZ_FWR   = 2 * SZ_FCW;                 //  3,145,728
    // G1: rh6 -> hep -> gp4 -> pre2 (pairwise time-disjoint)
    constexpr size_t SZ_G1    = SZ_PRE2;                    //  9,437,184 (max)
    constexpr size_t NEED = 2 * SZ_WT + SZ_WT1R + SZ_FWR + 2 * SZ_CAT
                          + 2 * SZ_GATG + 2 * SZ_NCG + SZ_HIDX + SZ_G1;  // 68,157,440

    if (ws_size >= NEED) {
        char* p = (char*)d_ws;
        short* wt_hi   = (short*)p; p += SZ_WT;
        short* wt_lo   = (short*)p; p += SZ_WT;
        char*  wt1r    = p;         p += SZ_WT1R;
        char*  fwr     = p;         p += SZ_FWR;
        short* cat_hi  = (short*)p; p += SZ_CAT;
        short* cat_lo  = (short*)p; p += SZ_CAT;
        short* gatg_hi = (short*)p; p += SZ_GATG;
        short* gatg_lo = (short*)p; p += SZ_GATG;
        short* ncg_hi  = (short*)p; p += SZ_NCG;
        short* ncg_lo  = (short*)p; p += SZ_NCG;
        float* hidx    = (float*)p; p += SZ_HIDX;
        char*  g1      = p;

        short* wt1_hi = (short*)wt1r;
        short* wt1_lo = (short*)(wt1r + SZ_WT1);
        float* wv6    = (float*)wt1r;                 // after wt1 dead
        float* wval   = (float*)(wt1r + SZ_WV6);      // after wt1 dead
        short* fcw_hi = (short*)fwr;
        short* fcw_lo = (short*)(fwr + SZ_FCW);
        short* trw_hi = (short*)fwr;                  // after fcw dead
        short* trw_lo = (short*)(fwr + SZ_FCW);
        float* rh6    = (float*)g1;
        float* hep    = (float*)g1;                   // after rh6 dead
        float* gp4    = (float*)g1;                   // after hep dead
        float* pre2   = (float*)g1;                   // after gp4 dead

        // 1. weight transpose-split (W_full, W_full1)
        convt_k<<<dim3(KCAT / 64, 96), 256, 0, stream>>>(W_full, wt_hi, wt_lo,
                                                         W_full1, wt1_hi, wt1_lo);
        // 2. fc_w split
        convw_k<<<MM * KXC / 8 / 256, 256, 0, stream>>>(fc_w, fcw_hi, fcw_lo);
        // 3. activations split -> cat
        prep_k<<<BB * KXC / 4 / 256, 256, 0, stream>>>(x, c, cat_hi, cat_lo);
        // 4. read_head partials (split-K 6)
        mgemm_k<0><<<dim3(MM / 128, BB / 64, 6), 256, 0, stream>>>(
            cat_hi, cat_lo, KCAT, nullptr, nullptr, 0,
            fcw_hi, fcw_lo, KXC, fc_b, rh6, MM, (size_t)BB * MM, KXC / 6);
        // 5. softmax -> hidx; h_entry partials; finish into cat
        smax_k<<<BB, 512, 0, stream>>>(rh6, hidx);
        hepart_k<<<dim3(BB, 4), 512, 0, stream>>>(hidx, hmem, hep);
        hefin_k<<<BB * RR / 256, 256, 0, stream>>>(hep, cat_hi, cat_lo);
        // 6. gate partials (split-K 4)
        mgemm_k<0><<<dim3(NG / 128, BB / 64, 4), 256, 0, stream>>>(
            cat_hi, cat_lo, KCAT, nullptr, nullptr, 0,
            wt1_hi, wt1_lo, KCAT, bias1, gp4, NG, (size_t)BB * NG, KCAT / 4);
        // 7. gate finish -> gatg
        gfin_k<<<BB * NG / 256, 256, 0, stream>>>(gp4, cat_hi, cat_lo, gatg_hi, gatg_lo);
        // 8. pre partials (split-K 2); A gathered: k<512 cat (=x), else gatg
        mgemm_k<1><<<dim3(NFULL / 128, BB / 64, 2), 256, 0, stream>>>(
            cat_hi, cat_lo, KCAT, gatg_hi, gatg_lo, NG,
            wt_hi, wt_lo, KCAT, bias, pre2, NFULL, (size_t)BB * NFULL, KCAT / 2);
        // 9. LSTM elementwise -> out, ncg
        lstm_k<<<BB * 1536 / 256, 256, 0, stream>>>(pre2, c, cat_hi, cat_lo,
                                                    out, ncg_hi, ncg_lo);
        // 10. trans_w split (into fcw's region — fcw dead)
        convw_k<<<RR * KXC / 8 / 256, 256, 0, stream>>>(trans_w, trw_hi, trw_lo);
        // 11. w_val partials (split-K 6); A gathered: k<512 cat (=x), else ncg
        mgemm_k<1><<<dim3(RR / 128, BB / 64, 6), 256, 0, stream>>>(
            cat_hi, cat_lo, KCAT, ncg_hi, ncg_lo, HH,
            trw_hi, trw_lo, KXC, trans_b, wv6, RR, (size_t)BB * RR, KXC / 6);
        // 12. collapse w_val partials
        wvred_k<<<BB * RR / 4 / 256, 256, 0, stream>>>(wv6, wval);
        // 13. hmem blend
        hmemupd_k<<<4096, 256, 0, stream>>>(hmem, wval, hidx, out + OFF_HM);
    } else {
        // -------- fallback: round-3 path (~10 MB ws) --------
        float* ws      = (float*)d_ws;
        float* hidx    = ws;
        float* concatb = hidx + BB * MM;
        float* gated   = concatb + BB * KCAT;
        float* pre     = gated + BB * KCAT;
        float* wval    = pre + BB * NFULL;
        float* new_c   = out + OFF_NC;

        prep3_k<<<BB * KXC / 256, 256, 0, stream>>>(x, c, concatb, gated);
        mgemm3_k<1, 1, 0><<<dim3(MM / 64, BB / 64), 256, 0, stream>>>(
            x, c, fc_w, fc_b, hidx, nullptr, MM, KXC);
        softmax3_k<<<BB, 256, 0, stream>>>(hidx);
        hentry3_k<<<BB, 512, 0, stream>>>(hidx, hmem, concatb);
        mgemm3_k<0, 0, 1><<<dim3(NG / 64, BB / 64), 256, 0, stream>>>(
            concatb, nullptr, W_full1, bias1, gated, concatb, NG, KCAT);
        mgemm3_k<0, 0, 0><<<dim3(NFULL / 64, BB / 64), 256, 0, stream>>>(
            gated, nullptr, W_full, bias, pre, nullptr, NFULL, KCAT);
        lstm3_k<<<BB * 1536 / 256, 256, 0, stream>>>(pre, c, concatb, out);
        mgemm3_k<1, 1, 0><<<dim3(RR / 64, BB / 64), 256, 0, stream>>>(
            x, new_c, trans_w, trans_b, wval, nullptr, RR, KXC);
        hmemupd_k<<<4096, 256, 0, stream>>>(hmem, wval, hidx, out + OFF_HM);
    }
}